// Round 3
// baseline (83.287 us; speedup 1.0000x reference)
//
#include <hip/hip_runtime.h>
#include <math.h>

#define BB 128
#define CC 1024
#define SPLIT 16                // blocks per batch
#define CHUNK (CC / SPLIT)      // 64 i's per block (one per lane)
#define NBLK (BB * SPLIT)       // 2048, power of 2
#define INV_N (1.0f / (float)(BB * CC))

// One single-wave block per (batch, chunk). Fused: partial compute + last-block
// deterministic final reduction (threadfence-reduction pattern).
// Counter trigger is modular: works for ANY starting counter value (poison-safe),
// since one call's 2048 atomic increments form a contiguous range.
__global__ __launch_bounds__(64) void asl_fused_kernel(
    const float* __restrict__ x, const float* __restrict__ y,
    const float* __restrict__ mask, float* __restrict__ partial,
    unsigned int* __restrict__ counter, float* __restrict__ out) {
  const int blk   = blockIdx.x;
  const int b     = blk & (BB - 1);   // consecutive blocks: different batch -> XCD spread
  const int chunk = blk >> 7;
  const int i0    = chunk * CHUNK;
  const int lane  = threadIdx.x;

  __shared__ unsigned short jidx[CC]; // compacted nonzero-y column indices
  __shared__ float          jw[CC];   // x[b,j]^2 for those columns

  const float* xb = x + (size_t)b * CC;
  const float* yb = y + (size_t)b * CC;

  // ---- negative term: exactly one i per lane ----
  const int   i  = i0 + lane;
  const float xi = xb[i];
  const float yi = yb[i];
  float acc = 0.0f;
  if (yi == 0.0f) {
    const float x2 = xi * xi;
    acc = (x2 * x2) * logf(1.0f - xi);   // xp = x; xp^4 * log(1-xp)
  }

  // ---- compact the full row's nonzero-y entries (single wave, no barrier) ----
  const float4* x4 = (const float4*)xb;
  const float4* y4 = (const float4*)yb;
  float4 xq[4], yq[4];
#pragma unroll
  for (int c = 0; c < 4; ++c) {
    xq[c] = x4[lane + 64 * c];
    yq[c] = y4[lane + 64 * c];
  }
  int base = 0;
#pragma unroll
  for (int c = 0; c < 4; ++c) {
    const float yv[4] = {yq[c].x, yq[c].y, yq[c].z, yq[c].w};
    const float xv[4] = {xq[c].x, xq[c].y, xq[c].z, xq[c].w};
#pragma unroll
    for (int q = 0; q < 4; ++q) {
      const bool p = (yv[q] != 0.0f);
      const unsigned long long bal = __ballot(p);
      if (p) {
        const int pos = base + __popcll(bal & ((1ull << lane) - 1ull));
        jidx[pos] = (unsigned short)(4 * (lane + 64 * c) + q);
        jw[pos]   = xv[q] * xv[q];
      }
      base += __popcll(bal);
    }
  }
  const int n = base;  // wave-uniform

  // ---- positive terms: entries dealt round-robin across the batch's blocks ----
  for (int e = chunk; e < n; e += SPLIT) {
    const int ii = jidx[e];                      // uniform LDS broadcast
    const float* mrow = mask + (size_t)ii * CC;
    float mm = 0.0f;
    for (int k = lane; k < n; k += 64)
      mm = fmaxf(mm, mrow[jidx[k]] * jw[k]);     // mask is 0/1; diag => mm > 0
#pragma unroll
    for (int off = 32; off > 0; off >>= 1)
      mm = fmaxf(mm, __shfl_xor(mm, off, 64));
    if (lane == 0) acc += logf(mm);              // GAMMA_POS = 0 -> just log(xp)
  }

  // ---- wave reduce, publish partial ----
#pragma unroll
  for (int off = 32; off > 0; off >>= 1)
    acc += __shfl_down(acc, off, 64);
  if (lane == 0) partial[blk] = acc;
  __threadfence();                               // device-scope release

  unsigned int old = 0;
  if (lane == 0) old = atomicAdd(counter, 1u);   // device-scope
  old = (unsigned int)__shfl((int)old, 0, 64);   // broadcast lane 0
  if ((old & (NBLK - 1u)) == (NBLK - 1u)) {
    // last-arriving block: deterministic final reduction in fixed order
    __threadfence();                             // device-scope acquire
    float v = 0.0f;
    for (int p = lane; p < NBLK; p += 64) v += partial[p];
#pragma unroll
    for (int off = 32; off > 0; off >>= 1)
      v += __shfl_down(v, off, 64);
    if (lane == 0) out[0] = -v * INV_N;
  }
}

extern "C" void kernel_launch(void* const* d_in, const int* in_sizes, int n_in,
                              void* d_out, int out_size, void* d_ws, size_t ws_size,
                              hipStream_t stream) {
  const float* x    = (const float*)d_in[0];
  const float* y    = (const float*)d_in[1];
  const float* mask = (const float*)d_in[2];
  float* out = (float*)d_out;
  float* partial = (float*)d_ws;                         // NBLK floats
  unsigned int* counter =
      (unsigned int*)((char*)d_ws + NBLK * sizeof(float)); // 1 uint, any init OK

  asl_fused_kernel<<<NBLK, 64, 0, stream>>>(x, y, mask, partial, counter, out);
}

// Round 4
// 23.678 us; speedup vs baseline: 3.5175x; 3.5175x over previous
//
#include <hip/hip_runtime.h>
#include <math.h>

#define BB 128
#define CC 1024
#define INV_N (1.0f / (float)(BB * CC))

// One block (256 threads) per batch.
//  - negatives: each thread handles its own float4 of the row
//  - compaction: each wave compacts its quarter (ballot+prefix), stitched via LDS
//  - positives: wave 0; lane e owns compacted entry e, loops over all k with
//    uniform (jidx[k], jw[k]) broadcasts -> ~n independent pipelined gathers,
//    one logf per entry, no per-entry cross-lane reduction.
__global__ __launch_bounds__(256) void asl_main_kernel(
    const float* __restrict__ x, const float* __restrict__ y,
    const float* __restrict__ mask, float* __restrict__ partial) {
  const int b    = blockIdx.x;
  const int tid  = threadIdx.x;
  const int lane = tid & 63;
  const int wid  = tid >> 6;

  __shared__ unsigned short jidx[CC];
  __shared__ float          jw[CC];
  __shared__ int            wcnt[4];
  __shared__ float          red[4];

  const float* xb = x + (size_t)b * CC;
  const float* yb = y + (size_t)b * CC;

  // Each thread loads 4 consecutive elements.
  const float4 xq = ((const float4*)xb)[tid];
  const float4 yq = ((const float4*)yb)[tid];
  const float xa[4] = {xq.x, xq.y, xq.z, xq.w};
  const float ya[4] = {yq.x, yq.y, yq.z, yq.w};

  // ---- negative terms ----
  float acc = 0.0f;
#pragma unroll
  for (int q = 0; q < 4; ++q) {
    if (ya[q] == 0.0f) {
      const float x2 = xa[q] * xa[q];
      acc += (x2 * x2) * logf(1.0f - xa[q]);   // xp = x; xp^4 * log(1-xp)
    }
  }

  // ---- parallel compaction: each wave compacts its 256-element quarter ----
  bool p4[4];
  int  ppos[4];
  int  cnt = 0;
#pragma unroll
  for (int q = 0; q < 4; ++q) {
    const bool p = (ya[q] != 0.0f);
    const unsigned long long bal = __ballot(p);
    p4[q]   = p;
    ppos[q] = cnt + __popcll(bal & ((1ull << lane) - 1ull));
    cnt    += __popcll(bal);
  }
  if (lane == 0) wcnt[wid] = cnt;
  __syncthreads();
  int off = 0;
  for (int w = 0; w < wid; ++w) off += wcnt[w];
  const int n = wcnt[0] + wcnt[1] + wcnt[2] + wcnt[3];
#pragma unroll
  for (int q = 0; q < 4; ++q) {
    if (p4[q]) {
      const int pos = off + ppos[q];
      jidx[pos] = (unsigned short)(4 * tid + q);
      jw[pos]   = xa[q] * xa[q];
    }
  }
  __syncthreads();

  // ---- positive terms: wave 0, lane-owns-entry, serial-k with broadcasts ----
  if (wid == 0) {
    for (int s = 0; s * 64 < n; ++s) {               // usually 1 iteration
      const int  e      = s * 64 + lane;
      const bool active = (e < n);
      const float* mrow = mask + (size_t)(active ? jidx[e] : 0) * CC;
      float mm = 0.0f;
#pragma unroll 4
      for (int k = 0; k < n; ++k) {
        // jidx[k]/jw[k] are wave-uniform LDS broadcasts; loads are independent.
        mm = fmaxf(mm, mrow[jidx[k]] * jw[k]);       // mask is 0/1; diag => mm>0
      }
      if (active) acc += logf(mm);                   // GAMMA_POS=0 -> log(xp)
    }
  }

  // ---- block reduction ----
#pragma unroll
  for (int o = 32; o > 0; o >>= 1)
    acc += __shfl_down(acc, o, 64);
  if (lane == 0) red[wid] = acc;
  __syncthreads();
  if (tid == 0) partial[b] = red[0] + red[1] + red[2] + red[3];
}

// Deterministic 128 -> 1 reduction, negated mean.
__global__ __launch_bounds__(64) void asl_final_kernel(
    const float* __restrict__ partial, float* __restrict__ out) {
  const int lane = threadIdx.x;
  float v = partial[lane] + partial[lane + 64];
#pragma unroll
  for (int o = 32; o > 0; o >>= 1)
    v += __shfl_down(v, o, 64);
  if (lane == 0) out[0] = -v * INV_N;
}

extern "C" void kernel_launch(void* const* d_in, const int* in_sizes, int n_in,
                              void* d_out, int out_size, void* d_ws, size_t ws_size,
                              hipStream_t stream) {
  const float* x    = (const float*)d_in[0];
  const float* y    = (const float*)d_in[1];
  const float* mask = (const float*)d_in[2];
  float* out     = (float*)d_out;
  float* partial = (float*)d_ws;   // BB floats, fully rewritten each call

  asl_main_kernel<<<BB, 256, 0, stream>>>(x, y, mask, partial);
  asl_final_kernel<<<1, 64, 0, stream>>>(partial, out);
}

// Round 5
// 14.661 us; speedup vs baseline: 5.6807x; 1.6150x over previous
//
#include <hip/hip_runtime.h>
#include <math.h>

#define BB 128
#define CC 1024
#define SPLIT 16                 // blocks per batch
#define CHUNK (CC / SPLIT)       // 64 i's per block (one per lane)
#define NBLK (BB * SPLIT)        // 2048
#define INV_N (1.0f / (float)(BB * CC))

// One single-wave block per (batch, chunk). No barriers, no atomics.
//  - negatives: one i per lane (i = chunk*64 + lane)
//  - compaction: 16 ballots over the full row (held in 4 float4/lane)
//  - positives: entries dealt round-robin by index (e % SPLIT == chunk);
//    each is a 64-lane gather over the ~51 compacted columns + shfl-max.
__global__ __launch_bounds__(64) void asl_main_kernel(
    const float* __restrict__ x, const float* __restrict__ y,
    const float* __restrict__ mask, float* __restrict__ partial) {
  const int blk   = blockIdx.x;
  const int b     = blk & (BB - 1);   // consecutive blocks: different batch
  const int chunk = blk >> 7;
  const int lane  = threadIdx.x;

  __shared__ unsigned short jidx[CC];
  __shared__ float          jw[CC];

  const float* xb = x + (size_t)b * CC;
  const float* yb = y + (size_t)b * CC;

  // Full row into registers (for compaction).
  const float4* x4 = (const float4*)xb;
  const float4* y4 = (const float4*)yb;
  float4 xq[4], yq[4];
#pragma unroll
  for (int c = 0; c < 4; ++c) {
    xq[c] = x4[lane + 64 * c];
    yq[c] = y4[lane + 64 * c];
  }

  // Negative term: one i per lane (scalar loads, cache-hot).
  const int   i  = chunk * CHUNK + lane;
  const float xi = xb[i];
  const float yi = yb[i];

  // ---- compaction: 16 ballots, deterministic order ----
  int base = 0;
#pragma unroll
  for (int c = 0; c < 4; ++c) {
    const float yv[4] = {yq[c].x, yq[c].y, yq[c].z, yq[c].w};
    const float xv[4] = {xq[c].x, xq[c].y, xq[c].z, xq[c].w};
#pragma unroll
    for (int q = 0; q < 4; ++q) {
      const bool p = (yv[q] != 0.0f);
      const unsigned long long bal = __ballot(p);
      if (p) {
        const int pos = base + __popcll(bal & ((1ull << lane) - 1ull));
        jidx[pos] = (unsigned short)(4 * (lane + 64 * c) + q);
        jw[pos]   = xv[q] * xv[q];
      }
      base += __popcll(bal);
    }
  }
  const int n = base;  // wave-uniform

  float acc = 0.0f;

  // ---- positives: entries e with e % SPLIT == chunk ----
  for (int e = chunk; e < n; e += SPLIT) {
    const int ii = jidx[e];                        // uniform LDS broadcast
    const float* mrow = mask + (size_t)ii * CC;
    float mm = 0.0f;
    for (int k = lane; k < n; k += 64)             // one round trip (n<=64 typ.)
      mm = fmaxf(mm, mrow[jidx[k]] * jw[k]);       // mask is 0/1; diag => mm>0
#pragma unroll
    for (int o = 32; o > 0; o >>= 1)
      mm = fmaxf(mm, __shfl_xor(mm, o, 64));
    if (lane == 0) acc += logf(mm);                // GAMMA_POS=0 -> log(xp)
  }

  // ---- negatives ----
  if (yi == 0.0f) {
    const float x2 = xi * xi;
    acc += (x2 * x2) * logf(1.0f - xi);            // xp = x; xp^4*log(1-xp)
  }

  // ---- wave reduce, publish ----
#pragma unroll
  for (int o = 32; o > 0; o >>= 1)
    acc += __shfl_down(acc, o, 64);
  if (lane == 0) partial[blk] = acc;
}

// Deterministic NBLK -> 1 reduction, negated mean.
__global__ __launch_bounds__(256) void asl_final_kernel(
    const float* __restrict__ partial, float* __restrict__ out) {
  const int tid = threadIdx.x;
  float v = 0.0f;
  for (int p = tid; p < NBLK; p += 256) v += partial[p];
#pragma unroll
  for (int o = 32; o > 0; o >>= 1)
    v += __shfl_down(v, o, 64);
  __shared__ float s[4];
  if ((tid & 63) == 0) s[tid >> 6] = v;
  __syncthreads();
  if (tid == 0) out[0] = -(s[0] + s[1] + s[2] + s[3]) * INV_N;
}

extern "C" void kernel_launch(void* const* d_in, const int* in_sizes, int n_in,
                              void* d_out, int out_size, void* d_ws, size_t ws_size,
                              hipStream_t stream) {
  const float* x    = (const float*)d_in[0];
  const float* y    = (const float*)d_in[1];
  const float* mask = (const float*)d_in[2];
  float* out     = (float*)d_out;
  float* partial = (float*)d_ws;   // NBLK floats, fully rewritten each call

  asl_main_kernel<<<NBLK, 64, 0, stream>>>(x, y, mask, partial);
  asl_final_kernel<<<1, 256, 0, stream>>>(partial, out);
}